// Round 5
// baseline (314.152 us; speedup 1.0000x reference)
//
#include <hip/hip_runtime.h>

// MSE-sum loss: out[0] = 0.5 * sum((a[i]-b[i])^2), n = 40e6 fp32 per input.
//
// R10 analysis: R9 (sc0 sc1 system-scope bypass) NULL vs builtin nt -> the
// plateau is not about allocation depth. Counter history shows two distinct
// read paths with different ceilings:
//   cached (MALL-hit, no-nt): 2.86 TB/s  [R1: FETCH_SIZE ~155 KB -> ~all hits]
//   streaming (HBM, nt):      3.9  TB/s  [R2/R4]
//   write-only fill:          6.86 TB/s  (demonstrated fabric rate)
// All kernels so far pushed 100% of traffic down ONE path. Change: split
// traffic 7:9 (cached:nt) per 16-block group, interleaved so both paths run
// concurrently. Balance: 140 MB / 2.9 = 48 us cached || 180 MB / 3.9 = 46 us
// nt. Cached footprint 140 MB < 256 MB MALL -> resident across iterations
// (proven by R1's FETCH~0 despite the 640 MB poison fills).
// Prediction: stage1 ~48-58 us, total ~265-278, stage1 FETCH ~180 MB.
// Null (294 +- 3) => paths share one limiter => read-fabric roofline.

typedef float fvec4 __attribute__((ext_vector_type(4)));

#define V4_PER_BLOCK 2048L   // 256 threads * 8 float4 each, per input array
#define CACHED_MOD 16
#define CACHED_CNT 7         // 7 of every 16 blocks use caching loads

template<bool NT>
__device__ __forceinline__ fvec4 ld1(const fvec4* __restrict__ p) {
    if constexpr (NT) return __builtin_nontemporal_load(p);
    else              return *p;
}

template<bool NT>
__device__ __forceinline__ void accum_full(const fvec4* __restrict__ a4,
                                           const fvec4* __restrict__ b4,
                                           long base, int t,
                                           float& acc0, float& acc1,
                                           float& acc2, float& acc3) {
    // 16 independent loads in flight, a/b pairwise (proven R7 pattern).
    fvec4 x0 = ld1<NT>(&a4[base + 0*256 + t]);
    fvec4 y0 = ld1<NT>(&b4[base + 0*256 + t]);
    fvec4 x1 = ld1<NT>(&a4[base + 1*256 + t]);
    fvec4 y1 = ld1<NT>(&b4[base + 1*256 + t]);
    fvec4 x2 = ld1<NT>(&a4[base + 2*256 + t]);
    fvec4 y2 = ld1<NT>(&b4[base + 2*256 + t]);
    fvec4 x3 = ld1<NT>(&a4[base + 3*256 + t]);
    fvec4 y3 = ld1<NT>(&b4[base + 3*256 + t]);
    fvec4 x4 = ld1<NT>(&a4[base + 4*256 + t]);
    fvec4 y4 = ld1<NT>(&b4[base + 4*256 + t]);
    fvec4 x5 = ld1<NT>(&a4[base + 5*256 + t]);
    fvec4 y5 = ld1<NT>(&b4[base + 5*256 + t]);
    fvec4 x6 = ld1<NT>(&a4[base + 6*256 + t]);
    fvec4 y6 = ld1<NT>(&b4[base + 6*256 + t]);
    fvec4 x7 = ld1<NT>(&a4[base + 7*256 + t]);
    fvec4 y7 = ld1<NT>(&b4[base + 7*256 + t]);

    fvec4 d;
    d = x0 - y0; acc0 = fmaf(d.x, d.x, acc0); acc1 = fmaf(d.y, d.y, acc1);
                 acc2 = fmaf(d.z, d.z, acc2); acc3 = fmaf(d.w, d.w, acc3);
    d = x1 - y1; acc0 = fmaf(d.x, d.x, acc0); acc1 = fmaf(d.y, d.y, acc1);
                 acc2 = fmaf(d.z, d.z, acc2); acc3 = fmaf(d.w, d.w, acc3);
    d = x2 - y2; acc0 = fmaf(d.x, d.x, acc0); acc1 = fmaf(d.y, d.y, acc1);
                 acc2 = fmaf(d.z, d.z, acc2); acc3 = fmaf(d.w, d.w, acc3);
    d = x3 - y3; acc0 = fmaf(d.x, d.x, acc0); acc1 = fmaf(d.y, d.y, acc1);
                 acc2 = fmaf(d.z, d.z, acc2); acc3 = fmaf(d.w, d.w, acc3);
    d = x4 - y4; acc0 = fmaf(d.x, d.x, acc0); acc1 = fmaf(d.y, d.y, acc1);
                 acc2 = fmaf(d.z, d.z, acc2); acc3 = fmaf(d.w, d.w, acc3);
    d = x5 - y5; acc0 = fmaf(d.x, d.x, acc0); acc1 = fmaf(d.y, d.y, acc1);
                 acc2 = fmaf(d.z, d.z, acc2); acc3 = fmaf(d.w, d.w, acc3);
    d = x6 - y6; acc0 = fmaf(d.x, d.x, acc0); acc1 = fmaf(d.y, d.y, acc1);
                 acc2 = fmaf(d.z, d.z, acc2); acc3 = fmaf(d.w, d.w, acc3);
    d = x7 - y7; acc0 = fmaf(d.x, d.x, acc0); acc1 = fmaf(d.y, d.y, acc1);
                 acc2 = fmaf(d.z, d.z, acc2); acc3 = fmaf(d.w, d.w, acc3);
}

__global__ __launch_bounds__(256) void mse_stage1(const fvec4* __restrict__ a4,
                                                  const fvec4* __restrict__ b4,
                                                  float* __restrict__ partial,
                                                  long n4) {
    const int t = threadIdx.x;
    const long base = (long)blockIdx.x * V4_PER_BLOCK;

    float acc0 = 0.0f, acc1 = 0.0f, acc2 = 0.0f, acc3 = 0.0f;

    if (base + V4_PER_BLOCK <= n4) {
        // Path split, interleaved at 16-block (2 MB) granularity so the
        // MALL path and the HBM-streaming path are concurrently active.
        if ((blockIdx.x % CACHED_MOD) < CACHED_CNT)
            accum_full<false>(a4, b4, base, t, acc0, acc1, acc2, acc3);  // cached
        else
            accum_full<true>(a4, b4, base, t, acc0, acc1, acc2, acc3);   // nt stream
    } else {
        // Tail block only (uniform branch): guarded plain loads.
        #pragma unroll
        for (int u = 0; u < 8; ++u) {
            const long i = base + (long)u * 256 + t;
            if (i < n4) {
                fvec4 xv = a4[i];
                fvec4 yv = b4[i];
                fvec4 d = xv - yv;
                acc0 = fmaf(d.x, d.x, acc0);
                acc1 = fmaf(d.y, d.y, acc1);
                acc2 = fmaf(d.z, d.z, acc2);
                acc3 = fmaf(d.w, d.w, acc3);
            }
        }
    }

    float acc = (acc0 + acc1) + (acc2 + acc3);

    // wave-64 shuffle reduction
    #pragma unroll
    for (int off = 32; off > 0; off >>= 1)
        acc += __shfl_down(acc, off, 64);

    __shared__ float wave_sums[4];
    const int lane = t & 63;
    const int wid  = t >> 6;
    if (lane == 0) wave_sums[wid] = acc;
    __syncthreads();

    if (t == 0)
        partial[blockIdx.x] = (wave_sums[0] + wave_sums[1]) + (wave_sums[2] + wave_sums[3]);
}

__global__ __launch_bounds__(256) void mse_stage2(const float* __restrict__ partial,
                                                  float* __restrict__ out,
                                                  int m) {
    float acc = 0.0f;
    for (int i = threadIdx.x; i < m; i += 256)
        acc += partial[i];

    #pragma unroll
    for (int off = 32; off > 0; off >>= 1)
        acc += __shfl_down(acc, off, 64);

    __shared__ float wave_sums[4];
    const int lane = threadIdx.x & 63;
    const int wid  = threadIdx.x >> 6;
    if (lane == 0) wave_sums[wid] = acc;
    __syncthreads();

    if (threadIdx.x == 0)
        out[0] = 0.5f * ((wave_sums[0] + wave_sums[1]) + (wave_sums[2] + wave_sums[3]));
}

extern "C" void kernel_launch(void* const* d_in, const int* in_sizes, int n_in,
                              void* d_out, int out_size, void* d_ws, size_t ws_size,
                              hipStream_t stream) {
    const fvec4* a4 = (const fvec4*)d_in[0];
    const fvec4* b4 = (const fvec4*)d_in[1];
    float* out = (float*)d_out;
    float* partial = (float*)d_ws;

    const long n = (long)in_sizes[0];        // 40,000,000 floats per input
    const long n4 = n >> 2;                  // 10,000,000 float4 groups (n % 4 == 0)
    const int blocks = (int)((n4 + V4_PER_BLOCK - 1) / V4_PER_BLOCK);   // 4883

    mse_stage1<<<blocks, 256, 0, stream>>>(a4, b4, partial, n4);
    mse_stage2<<<1, 256, 0, stream>>>(partial, out, blocks);
}

// Round 6
// 292.868 us; speedup vs baseline: 1.0727x; 1.0727x over previous
//
#include <hip/hip_runtime.h>

// MSE-sum loss: out[0] = 0.5 * sum((a[i]-b[i])^2), n = 40e6 fp32 per input.
//
// R11: REVERT to best (R7, 294.5 us) + roofline declaration.
// Final evidence table (6 probes):
//   no-nt reads:        2.86 TB/s (cached route)
//   nt reads:           3.90 TB/s -- invariant over 3 structures, 2 patterns,
//                       sc0/sc1 scope bits, occupancy
//   mixed 7:9 split:    3.14 TB/s blended (R5) -> paths SHARE one limiter,
//                       they do not sum
//   write-only fill:    6.86 TB/s (11.2 B/cyc/CU; fire-and-forget)
// Read cap ~3.9 TB/s = 6.35 B/cyc/CU == outstanding-miss-queue x ~900 cyc
// HBM latency bound; copy ubench (6.29 TB/s R+W ~ 3.15 each way) corroborates.
// Traffic (320 MB) is irreducible: (a-b)^2 requires paired reads of both
// buffers. stage1 ~82 us = 320 MB / 3.9 TB/s -> AT the read roofline.
// Remaining ~212 us of the 294 us total = harness poison fills (2 x ~93 us
// @ 86% HBM peak) + epsilon. No kernel-side lever remains.

typedef float fvec4 __attribute__((ext_vector_type(4)));

#define V4_PER_BLOCK 2048L   // 256 threads * 8 float4 each, per input array

__global__ __launch_bounds__(256) void mse_stage1(const fvec4* __restrict__ a4,
                                                  const fvec4* __restrict__ b4,
                                                  float* __restrict__ partial,
                                                  long n4) {
    const int t = threadIdx.x;
    const long base = (long)blockIdx.x * V4_PER_BLOCK;

    float acc0 = 0.0f, acc1 = 0.0f, acc2 = 0.0f, acc3 = 0.0f;

    if (base + V4_PER_BLOCK <= n4) {
        // Guard-free main path: 16 independent nontemporal global_load_dwordx4,
        // a/b interleaved pairwise. Lane i reads base + u*256 + i ->
        // perfectly coalesced 1 KB per quarter-wave group.
        fvec4 x0 = __builtin_nontemporal_load(&a4[base + 0*256 + t]);
        fvec4 y0 = __builtin_nontemporal_load(&b4[base + 0*256 + t]);
        fvec4 x1 = __builtin_nontemporal_load(&a4[base + 1*256 + t]);
        fvec4 y1 = __builtin_nontemporal_load(&b4[base + 1*256 + t]);
        fvec4 x2 = __builtin_nontemporal_load(&a4[base + 2*256 + t]);
        fvec4 y2 = __builtin_nontemporal_load(&b4[base + 2*256 + t]);
        fvec4 x3 = __builtin_nontemporal_load(&a4[base + 3*256 + t]);
        fvec4 y3 = __builtin_nontemporal_load(&b4[base + 3*256 + t]);
        fvec4 x4 = __builtin_nontemporal_load(&a4[base + 4*256 + t]);
        fvec4 y4 = __builtin_nontemporal_load(&b4[base + 4*256 + t]);
        fvec4 x5 = __builtin_nontemporal_load(&a4[base + 5*256 + t]);
        fvec4 y5 = __builtin_nontemporal_load(&b4[base + 5*256 + t]);
        fvec4 x6 = __builtin_nontemporal_load(&a4[base + 6*256 + t]);
        fvec4 y6 = __builtin_nontemporal_load(&b4[base + 6*256 + t]);
        fvec4 x7 = __builtin_nontemporal_load(&a4[base + 7*256 + t]);
        fvec4 y7 = __builtin_nontemporal_load(&b4[base + 7*256 + t]);

        fvec4 d;
        d = x0 - y0; acc0 = fmaf(d.x, d.x, acc0); acc1 = fmaf(d.y, d.y, acc1);
                     acc2 = fmaf(d.z, d.z, acc2); acc3 = fmaf(d.w, d.w, acc3);
        d = x1 - y1; acc0 = fmaf(d.x, d.x, acc0); acc1 = fmaf(d.y, d.y, acc1);
                     acc2 = fmaf(d.z, d.z, acc2); acc3 = fmaf(d.w, d.w, acc3);
        d = x2 - y2; acc0 = fmaf(d.x, d.x, acc0); acc1 = fmaf(d.y, d.y, acc1);
                     acc2 = fmaf(d.z, d.z, acc2); acc3 = fmaf(d.w, d.w, acc3);
        d = x3 - y3; acc0 = fmaf(d.x, d.x, acc0); acc1 = fmaf(d.y, d.y, acc1);
                     acc2 = fmaf(d.z, d.z, acc2); acc3 = fmaf(d.w, d.w, acc3);
        d = x4 - y4; acc0 = fmaf(d.x, d.x, acc0); acc1 = fmaf(d.y, d.y, acc1);
                     acc2 = fmaf(d.z, d.z, acc2); acc3 = fmaf(d.w, d.w, acc3);
        d = x5 - y5; acc0 = fmaf(d.x, d.x, acc0); acc1 = fmaf(d.y, d.y, acc1);
                     acc2 = fmaf(d.z, d.z, acc2); acc3 = fmaf(d.w, d.w, acc3);
        d = x6 - y6; acc0 = fmaf(d.x, d.x, acc0); acc1 = fmaf(d.y, d.y, acc1);
                     acc2 = fmaf(d.z, d.z, acc2); acc3 = fmaf(d.w, d.w, acc3);
        d = x7 - y7; acc0 = fmaf(d.x, d.x, acc0); acc1 = fmaf(d.y, d.y, acc1);
                     acc2 = fmaf(d.z, d.z, acc2); acc3 = fmaf(d.w, d.w, acc3);
    } else {
        // Tail block only (uniform branch): guarded nt loads.
        #pragma unroll
        for (int u = 0; u < 8; ++u) {
            const long i = base + (long)u * 256 + t;
            if (i < n4) {
                fvec4 xv = __builtin_nontemporal_load(&a4[i]);
                fvec4 yv = __builtin_nontemporal_load(&b4[i]);
                fvec4 d = xv - yv;
                acc0 = fmaf(d.x, d.x, acc0);
                acc1 = fmaf(d.y, d.y, acc1);
                acc2 = fmaf(d.z, d.z, acc2);
                acc3 = fmaf(d.w, d.w, acc3);
            }
        }
    }

    float acc = (acc0 + acc1) + (acc2 + acc3);

    // wave-64 shuffle reduction
    #pragma unroll
    for (int off = 32; off > 0; off >>= 1)
        acc += __shfl_down(acc, off, 64);

    __shared__ float wave_sums[4];
    const int lane = t & 63;
    const int wid  = t >> 6;
    if (lane == 0) wave_sums[wid] = acc;
    __syncthreads();

    if (t == 0)
        partial[blockIdx.x] = (wave_sums[0] + wave_sums[1]) + (wave_sums[2] + wave_sums[3]);
}

__global__ __launch_bounds__(256) void mse_stage2(const float* __restrict__ partial,
                                                  float* __restrict__ out,
                                                  int m) {
    float acc = 0.0f;
    for (int i = threadIdx.x; i < m; i += 256)
        acc += partial[i];

    #pragma unroll
    for (int off = 32; off > 0; off >>= 1)
        acc += __shfl_down(acc, off, 64);

    __shared__ float wave_sums[4];
    const int lane = threadIdx.x & 63;
    const int wid  = threadIdx.x >> 6;
    if (lane == 0) wave_sums[wid] = acc;
    __syncthreads();

    if (threadIdx.x == 0)
        out[0] = 0.5f * ((wave_sums[0] + wave_sums[1]) + (wave_sums[2] + wave_sums[3]));
}

extern "C" void kernel_launch(void* const* d_in, const int* in_sizes, int n_in,
                              void* d_out, int out_size, void* d_ws, size_t ws_size,
                              hipStream_t stream) {
    const fvec4* a4 = (const fvec4*)d_in[0];
    const fvec4* b4 = (const fvec4*)d_in[1];
    float* out = (float*)d_out;
    float* partial = (float*)d_ws;

    const long n = (long)in_sizes[0];        // 40,000,000 floats per input
    const long n4 = n >> 2;                  // 10,000,000 float4 groups (n % 4 == 0)
    const int blocks = (int)((n4 + V4_PER_BLOCK - 1) / V4_PER_BLOCK);   // 4883

    mse_stage1<<<blocks, 256, 0, stream>>>(a4, b4, partial, n4);
    mse_stage2<<<1, 256, 0, stream>>>(partial, out, blocks);
}